// Round 1
// baseline (50.638 us; speedup 1.0000x reference)
//
#include <hip/hip_runtime.h>

#define B_ 256
#define T_ 168
#define C_ 1024
#define H_ 24
#define PF 12   // prefetch chunk: 168 = 14 chunks of 12

// d_ws layout (floats): W[t*24 + k] for t in [0,168), k in [0,24); beta[k] at [168*24 + k]
// Total: 168*24 + 24 = 4056 floats = 16,224 bytes.

// One block. Thread t < 168 computes the whole column W[.][t] locally
// (W[k][t] depends only on W[j][t] for j<k -- same t, no cross-thread deps).
// Thread 168 computes beta.
__global__ __launch_bounds__(192) void ar_precompute(const float* __restrict__ w,
                                                     const float* __restrict__ bias,
                                                     float* __restrict__ ws) {
    __shared__ float lw[T_];
    const int t = threadIdx.x;
    if (t < T_) lw[t] = w[t];
    __syncthreads();
    if (t < T_) {
        float col[H_];
        #pragma unroll
        for (int k = 0; k < H_; ++k) {
            float v = (t >= k) ? lw[t - k] : 0.0f;
            #pragma unroll
            for (int j = 0; j < k; ++j)
                v += lw[T_ - k + j] * col[j];
            col[k] = v;
        }
        #pragma unroll
        for (int k = 0; k < H_; ++k)
            ws[t * H_ + k] = col[k];
    } else if (t == T_) {
        float bv = bias[0];
        float beta[H_];
        #pragma unroll
        for (int k = 0; k < H_; ++k) {
            float v = bv;
            #pragma unroll
            for (int j = 0; j < k; ++j)
                v += lw[T_ - k + j] * beta[j];
            beta[k] = v;
        }
        #pragma unroll
        for (int k = 0; k < H_; ++k)
            ws[T_ * H_ + k] = beta[k];
    }
}

// out[b,k,c] = beta[k] + sum_t W[k][t] * y[b,t,c]
// One thread per (b,c). grid = (C/256, B), block = 256.
// Software-pipelined: two PF-deep register buffers, 2x-unrolled outer loop so
// buffer alternation is static (no runtime-indexed arrays, no copy movs).
// Keeps a full 12-load chunk in flight while the previous chunk is consumed.
__global__ __launch_bounds__(256) void ar_main(const float* __restrict__ y,
                                               const float* __restrict__ ws,
                                               float* __restrict__ out) {
    const int c = blockIdx.x * 256 + threadIdx.x;
    const int b = blockIdx.y;
    const float* __restrict__ yp = y + (size_t)b * (size_t)(T_ * C_) + c;
    const float* __restrict__ beta = ws + T_ * H_;

    float acc[H_];
    #pragma unroll
    for (int k = 0; k < H_; ++k) acc[k] = beta[k];   // uniform load -> s_load

    float buf0[PF], buf1[PF];

    // load chunk ci into buf (coalesced across lanes; 12 independent loads)
    #define LOAD_CHUNK(buf, ci)                                            \
        {                                                                  \
            _Pragma("unroll")                                              \
            for (int i = 0; i < PF; ++i)                                   \
                buf[i] = yp[(size_t)((ci) * PF + i) * C_];                 \
        }

    // consume chunk ci from buf: 12 x 24 FMAs, W via uniform s_load_dwordx4
    #define COMP_CHUNK(buf, ci)                                            \
        {                                                                  \
            _Pragma("unroll")                                              \
            for (int i = 0; i < PF; ++i) {                                 \
                const float yv = buf[i];                                   \
                const float4* __restrict__ w4 =                            \
                    (const float4*)(ws + ((ci) * PF + i) * H_);            \
                _Pragma("unroll")                                          \
                for (int q = 0; q < H_ / 4; ++q) {                         \
                    const float4 wv = w4[q];                               \
                    acc[4 * q + 0] += wv.x * yv;                           \
                    acc[4 * q + 1] += wv.y * yv;                           \
                    acc[4 * q + 2] += wv.z * yv;                           \
                    acc[4 * q + 3] += wv.w * yv;                           \
                }                                                          \
            }                                                              \
        }

    // 14 chunks total: prologue loads chunk 0; 6 iterations handle chunks
    // 0..11 (load-ahead by one chunk); epilogue handles chunks 12, 13.
    LOAD_CHUNK(buf0, 0);
    for (int p = 0; p < 6; ++p) {
        const int ci = 2 * p;
        LOAD_CHUNK(buf1, ci + 1);
        COMP_CHUNK(buf0, ci);
        LOAD_CHUNK(buf0, ci + 2);
        COMP_CHUNK(buf1, ci + 1);
    }
    LOAD_CHUNK(buf1, 13);
    COMP_CHUNK(buf0, 12);
    COMP_CHUNK(buf1, 13);

    #undef LOAD_CHUNK
    #undef COMP_CHUNK

    float* __restrict__ op = out + ((size_t)b * H_) * C_ + c;
    #pragma unroll
    for (int k = 0; k < H_; ++k)
        op[(size_t)k * C_] = acc[k];                  // coalesced across lanes
}

extern "C" void kernel_launch(void* const* d_in, const int* in_sizes, int n_in,
                              void* d_out, int out_size, void* d_ws, size_t ws_size,
                              hipStream_t stream) {
    // inputs: 0=x (unused), 1=y (B,T,C), 2=w (1,168), 3=b (1,)
    const float* y    = (const float*)d_in[1];
    const float* w    = (const float*)d_in[2];
    const float* bias = (const float*)d_in[3];
    float* out = (float*)d_out;
    float* ws  = (float*)d_ws;

    ar_precompute<<<1, 192, 0, stream>>>(w, bias, ws);
    ar_main<<<dim3(C_ / 256, B_), 256, 0, stream>>>(y, ws, out);
}

// Round 2
// 47.815 us; speedup vs baseline: 1.0590x; 1.0590x over previous
//
#include <hip/hip_runtime.h>

#define B_ 256
#define T_ 168
#define C_ 1024
#define H_ 24

// Fused single-kernel version.
// Every block redundantly computes the unrolled AR weights W[t][k] and beta[k]
// (trivial: ~300 FMAs across 169 threads) into LDS, then runs the main
// contraction. This removes the 1-block precompute dispatch, its launch gap,
// and the global ws round-trip (round-0 two-kernel version: 44.2 us).
//
// Math: out[b,k,c] = beta[k] + sum_t W[k][t] * y[b,t,c]
// W recurrence per column t (depends only on same column, no cross-thread deps):
//   W[k][t] = w[t-k] (if t>=k else 0) + sum_{j<k} w[168-k+j] * W[j][t]
//   beta[k] = b + sum_{j<k} w[168-k+j] * beta[j]
//
// One thread per (b,c). grid = (C/256, B), block = 256.
__global__ __launch_bounds__(256) void ar_fused(const float* __restrict__ y,
                                                const float* __restrict__ w,
                                                const float* __restrict__ bias,
                                                float* __restrict__ out) {
    __shared__ float lw[T_];          // raw weights
    __shared__ float sW[T_ * H_];     // [t][k], 96 B per t (float4-aligned)
    __shared__ float sbeta[H_];

    const int tid = threadIdx.x;
    if (tid < T_) lw[tid] = w[tid];
    __syncthreads();

    if (tid < T_) {
        float col[H_];
        #pragma unroll
        for (int k = 0; k < H_; ++k) {
            float v = (tid >= k) ? lw[tid - k] : 0.0f;
            #pragma unroll
            for (int j = 0; j < k; ++j)
                v += lw[T_ - k + j] * col[j];
            col[k] = v;
        }
        #pragma unroll
        for (int k = 0; k < H_; ++k)
            sW[tid * H_ + k] = col[k];
    } else if (tid == T_) {
        float bv = bias[0];
        float beta[H_];
        #pragma unroll
        for (int k = 0; k < H_; ++k) {
            float v = bv;
            #pragma unroll
            for (int j = 0; j < k; ++j)
                v += lw[T_ - k + j] * beta[j];
            beta[k] = v;
        }
        #pragma unroll
        for (int k = 0; k < H_; ++k)
            sbeta[k] = beta[k];
    }
    __syncthreads();

    const int c = blockIdx.x * 256 + tid;
    const int b = blockIdx.y;
    const float* __restrict__ yp = y + (size_t)b * (size_t)(T_ * C_) + c;

    float acc[H_];
    #pragma unroll
    for (int k = 0; k < H_; ++k) acc[k] = sbeta[k];  // LDS broadcast

    #pragma unroll 4
    for (int t = 0; t < T_; ++t) {
        const float yv = yp[(size_t)t * C_];          // coalesced across lanes
        const float4* __restrict__ w4 = (const float4*)(sW + t * H_);
        #pragma unroll
        for (int q = 0; q < H_ / 4; ++q) {            // uniform addr -> broadcast ds_read_b128
            const float4 wv = w4[q];
            acc[4 * q + 0] += wv.x * yv;
            acc[4 * q + 1] += wv.y * yv;
            acc[4 * q + 2] += wv.z * yv;
            acc[4 * q + 3] += wv.w * yv;
        }
    }

    float* __restrict__ op = out + ((size_t)b * H_) * C_ + c;
    #pragma unroll
    for (int k = 0; k < H_; ++k)
        op[(size_t)k * C_] = acc[k];                  // coalesced across lanes
}

extern "C" void kernel_launch(void* const* d_in, const int* in_sizes, int n_in,
                              void* d_out, int out_size, void* d_ws, size_t ws_size,
                              hipStream_t stream) {
    // inputs: 0=x (unused), 1=y (B,T,C), 2=w (1,168), 3=b (1,)
    const float* y    = (const float*)d_in[1];
    const float* w    = (const float*)d_in[2];
    const float* bias = (const float*)d_in[3];
    float* out = (float*)d_out;

    ar_fused<<<dim3(C_ / 256, B_), 256, 0, stream>>>(y, w, bias, out);
}

// Round 3
// 40.849 us; speedup vs baseline: 1.2396x; 1.1705x over previous
//
#include <hip/hip_runtime.h>

#define B_ 256
#define T_ 168
#define C_ 1024
#define H_ 24
#define TH 84   // half of T: t-split factor 2

// d_ws layout (floats): W[t*24 + k] for t in [0,168), k in [0,24); beta[k] at [168*24 + k]
// Total: 168*24 + 24 = 4056 floats = 16,224 bytes.

// One block. Thread t < 168 computes the whole column W[.][t] locally
// (W[k][t] depends only on W[j][t] for j<k -- same t, no cross-thread deps).
// Thread 168 computes beta.
__global__ __launch_bounds__(192) void ar_precompute(const float* __restrict__ w,
                                                     const float* __restrict__ bias,
                                                     float* __restrict__ ws) {
    __shared__ float lw[T_];
    const int t = threadIdx.x;
    if (t < T_) lw[t] = w[t];
    __syncthreads();
    if (t < T_) {
        float col[H_];
        #pragma unroll
        for (int k = 0; k < H_; ++k) {
            float v = (t >= k) ? lw[t - k] : 0.0f;
            #pragma unroll
            for (int j = 0; j < k; ++j)
                v += lw[T_ - k + j] * col[j];
            col[k] = v;
        }
        #pragma unroll
        for (int k = 0; k < H_; ++k)
            ws[t * H_ + k] = col[k];
    } else if (t == T_) {
        float bv = bias[0];
        float beta[H_];
        #pragma unroll
        for (int k = 0; k < H_; ++k) {
            float v = bv;
            #pragma unroll
            for (int j = 0; j < k; ++j)
                v += lw[T_ - k + j] * beta[j];
            beta[k] = v;
        }
        #pragma unroll
        for (int k = 0; k < H_; ++k)
            ws[T_ * H_ + k] = beta[k];
    }
}

// out[b,k,c] = beta[k] + sum_t W[k][t] * y[b,t,c]
// t-split for TLP: block = 256 threads = 128 c-columns x 2 t-halves.
// Grid = (C/128, B) = 2048 blocks -> 8192 waves -> 8 waves/SIMD (was 4),
// doubling in-flight memory per SIMD with the round-0 inner loop unchanged.
// h=1 deposits partials in LDS ([24][128] transposed: stride-4B across lanes,
// conflict-free); h=0 reduces, adds beta, stores.
__global__ __launch_bounds__(256, 8) void ar_main(const float* __restrict__ y,
                                                  const float* __restrict__ ws,
                                                  float* __restrict__ out) {
    __shared__ float sacc[H_ * 128];

    const int tid = threadIdx.x;
    const int c_local = tid & 127;
    // tid>>7 is uniform across each wave (lanes 0-63 share it); force scalar so
    // W addresses stay provably uniform -> s_load_dwordx4 on the scalar pipe.
    const int h = __builtin_amdgcn_readfirstlane(tid >> 7);

    const int c = blockIdx.x * 128 + c_local;
    const int b = blockIdx.y;
    const float* __restrict__ yp =
        y + (size_t)b * (size_t)(T_ * C_) + (size_t)(h * TH) * C_ + c;

    float acc[H_];
    #pragma unroll
    for (int k = 0; k < H_; ++k) acc[k] = 0.0f;

    #pragma unroll 4
    for (int tt = 0; tt < TH; ++tt) {
        const float yv = yp[(size_t)tt * C_];          // coalesced across lanes
        const float4* __restrict__ w4 = (const float4*)(ws + (h * TH + tt) * H_);
        #pragma unroll
        for (int q = 0; q < H_ / 4; ++q) {             // uniform addr -> s_load_dwordx4
            const float4 wv = w4[q];
            acc[4 * q + 0] += wv.x * yv;
            acc[4 * q + 1] += wv.y * yv;
            acc[4 * q + 2] += wv.z * yv;
            acc[4 * q + 3] += wv.w * yv;
        }
    }

    if (h == 1) {
        #pragma unroll
        for (int k = 0; k < H_; ++k)
            sacc[k * 128 + c_local] = acc[k];          // conflict-free (4B stride)
    }
    __syncthreads();
    if (h == 0) {
        const float* __restrict__ beta = ws + T_ * H_; // uniform -> s_load
        float* __restrict__ op = out + ((size_t)b * H_) * C_ + c;
        #pragma unroll
        for (int k = 0; k < H_; ++k)
            op[(size_t)k * C_] = acc[k] + sacc[k * 128 + c_local] + beta[k];
    }
}

extern "C" void kernel_launch(void* const* d_in, const int* in_sizes, int n_in,
                              void* d_out, int out_size, void* d_ws, size_t ws_size,
                              hipStream_t stream) {
    // inputs: 0=x (unused), 1=y (B,T,C), 2=w (1,168), 3=b (1,)
    const float* y    = (const float*)d_in[1];
    const float* w    = (const float*)d_in[2];
    const float* bias = (const float*)d_in[3];
    float* out = (float*)d_out;
    float* ws  = (float*)d_ws;

    ar_precompute<<<1, 192, 0, stream>>>(w, bias, ws);
    ar_main<<<dim3(C_ / 128, B_), 256, 0, stream>>>(y, ws, out);
}